// Round 6
// baseline (89.909 us; speedup 1.0000x reference)
//
#include <hip/hip_runtime.h>
#include <math.h>

// BroadcastConv (max-plus conv): out[b,o,y,x] = max_{c,i,j} img[b,c,y+i-2,x+j-2] + kern[o,c,4-i,4-j]
// B=4, C=16, O=16, H=W=64, k=5x5, pad=2 with -inf.
//
// R6 = INSTRUMENTATION round. R5 body, repeated REPS times inside the kernel:
//  - per-rep rotation of wave->channel assignment ((wbase+rep)&7) makes each
//    rep non-hoistable while the per-rep union of channels (and the output)
//    is identical -> correctness preserved, stores idempotent.
//  - one dispatch of ~6x kernel cost ranks ABOVE the 40us harness fills in
//    rocprof top-5 -> finally get bconv's own VALUBusy/Occupancy/dur.
//  - marginal per-iter cost = (total - 65.74)/5.

#define NEG_INF (-__builtin_inff())
#define REPS 6

__global__ __launch_bounds__(512, 8) void bconv_kernel(
        const float* __restrict__ img,
        const float* __restrict__ kern,
        float* __restrict__ out) {
    const int x     = threadIdx.x & 63;    // lane = W col
    const int wbase = threadIdx.x >> 6;    // physical wave slot 0..7
    const int y  = blockIdx.x;
    const int og = blockIdx.y;
    const int b  = blockIdx.z;
    const int o0 = og * 4;

    __shared__ float red[8][4][64];

    const bool ok0 = (x >= 2);
    const bool ok1 = (x >= 1);
    const bool ok3 = (x <= 62);
    const bool ok4 = (x <= 61);

#pragma unroll 1
    for (int rep = 0; rep < REPS; ++rep) {
        // Rotated wave->channel-pair assignment; union over waves = all 16 c
        // for every rep, so each rep computes the identical full result.
        const int w  = __builtin_amdgcn_readfirstlane((wbase + rep) & 7);
        const int c0 = w * 2;

        float acc0 = NEG_INF, acc1 = NEG_INF, acc2 = NEG_INF, acc3 = NEG_INF;

#pragma unroll 1
        for (int cc = 0; cc < 2; ++cc) {
            const int c = c0 + cc;
            const float* __restrict__ pl  = img + ((b * 16 + c) << 12);
            const float* __restrict__ kp0 = kern + ((o0 + 0) * 16 + c) * 25;
            const float* __restrict__ kp1 = kern + ((o0 + 1) * 16 + c) * 25;
            const float* __restrict__ kp2 = kern + ((o0 + 2) * 16 + c) * 25;
            const float* __restrict__ kp3 = kern + ((o0 + 3) * 16 + c) * 25;

#pragma unroll
            for (int i = 0; i < 5; ++i) {
                const int yy = y + i - 2;
                if ((unsigned)yy >= 64u) continue;   // wave-uniform row skip
                float v2 = pl[(yy << 6) + x];
                float v0 = __shfl(v2, x - 2);
                float v1 = __shfl(v2, x - 1);
                float v3 = __shfl(v2, x + 1);
                float v4 = __shfl(v2, x + 2);
                v0 = ok0 ? v0 : NEG_INF;
                v1 = ok1 ? v1 : NEG_INF;
                v3 = ok3 ? v3 : NEG_INF;
                v4 = ok4 ? v4 : NEG_INF;

                const int kb = 24 - 5 * i;
#define ACC_O(kp, A)                                                     \
                {                                                        \
                    float t0 = v0 + kp[kb - 0];                          \
                    float t1 = v1 + kp[kb - 1];                          \
                    float t2 = v2 + kp[kb - 2];                          \
                    float t3 = v3 + kp[kb - 3];                          \
                    float t4 = v4 + kp[kb - 4];                          \
                    float m01  = fmaxf(t0, t1);                          \
                    float m234 = fmaxf(fmaxf(t2, t3), t4);               \
                    A = fmaxf(A, fmaxf(m01, m234));                      \
                }
                ACC_O(kp0, acc0)
                ACC_O(kp1, acc1)
                ACC_O(kp2, acc2)
                ACC_O(kp3, acc3)
#undef ACC_O
            }
        }

        red[wbase][0][x] = acc0;
        red[wbase][1][x] = acc1;
        red[wbase][2][x] = acc2;
        red[wbase][3][x] = acc3;
        __syncthreads();

        if (threadIdx.x < 256) {
            const int oo = threadIdx.x >> 6;
            float r = red[0][oo][x];
#pragma unroll
            for (int ww = 1; ww < 8; ++ww) r = fmaxf(r, red[ww][oo][x]);
            out[((b * 16 + o0 + oo) << 12) + (y << 6) + x] = r;
        }
        __syncthreads();   // red[] reused next rep (WAR)
    }
}

extern "C" void kernel_launch(void* const* d_in, const int* in_sizes, int n_in,
                              void* d_out, int out_size, void* d_ws, size_t ws_size,
                              hipStream_t stream) {
    const float* img  = (const float*)d_in[0];   // (4,16,64,64)
    const float* kern = (const float*)d_in[1];   // (16,16,5,5)
    float* out = (float*)d_out;                  // (4,16,64,64)
    (void)in_sizes; (void)n_in; (void)out_size; (void)d_ws; (void)ws_size;

    dim3 grid(64, 4, 4);   // y, o/4, b -> 1024 blocks * 8 waves = 32 waves/CU
    hipLaunchKernelGGL(bconv_kernel, grid, dim3(512), 0, stream, img, kern, out);
}

// Round 7
// 68.079 us; speedup vs baseline: 1.3207x; 1.3207x over previous
//
#include <hip/hip_runtime.h>
#include <math.h>

// BroadcastConv (max-plus conv): out[b,o,y,x] = max_{c,i,j} img[b,c,y+i-2,x+j-2] + kern[o,c,4-i,4-j]
// B=4, C=16, O=16, H=W=64, k=5x5, pad=2 with -inf.
//
// R7 (bconv measured at 4.83 us via R6 rep-instrumentation; harness floor ~61 us):
//  - neighbor columns via DPP wave_shr1/wave_shl1 with old=-inf, bound_ctrl off:
//    pure VALU (no ds_bpermute -> no lgkm conflation with weight s_loads) AND
//    edge lanes get -inf for free (chained shifts propagate it) -> all 40
//    cndmasks + masks deleted.
//  - packed f32 core: taps paired (j0,j1),(j2,j3) as <2 x float> ->
//    v_pk_add_f32 / v_pk_max_f32; tap j4 scalar. 10 -> 6 core inst per (o,row,c).
//  - weights on the scalar pipe (wave-uniform), same as R5.
//  - 512-thr blocks, 8 waves, c-split 8-way, 1024 blocks -> 32 waves/CU.

#define NEG_INF (-__builtin_inff())

typedef float f32x2 __attribute__((ext_vector_type(2)));

// lane i <- lane i-1 (column x-1); lane 0 -> -inf (old kept, bound_ctrl off)
__device__ __forceinline__ float sh_m1(float v) {
    return __int_as_float(__builtin_amdgcn_update_dpp(
        (int)0xFF800000, __float_as_int(v), 0x138, 0xF, 0xF, false));  // wave_shr1
}
// lane i <- lane i+1 (column x+1); lane 63 -> -inf
__device__ __forceinline__ float sh_p1(float v) {
    return __int_as_float(__builtin_amdgcn_update_dpp(
        (int)0xFF800000, __float_as_int(v), 0x130, 0xF, 0xF, false));  // wave_shl1
}

__global__ __launch_bounds__(512, 8) void bconv_kernel(
        const float* __restrict__ img,
        const float* __restrict__ kern,
        float* __restrict__ out) {
    const int x  = threadIdx.x & 63;                                   // lane = W col
    const int w  = __builtin_amdgcn_readfirstlane(threadIdx.x >> 6);   // wave id 0..7
    const int y  = blockIdx.x;
    const int og = blockIdx.y;
    const int b  = blockIdx.z;
    const int o0 = og * 4;
    const int c0 = w * 2;

    __shared__ float red[8][4][64];

    f32x2 accP[4];
    float accS[4];
#pragma unroll
    for (int oo = 0; oo < 4; ++oo) {
        accP[oo] = (f32x2){NEG_INF, NEG_INF};
        accS[oo] = NEG_INF;
    }

#pragma unroll 1                  // two serial c-iterations: keep VGPRs small
    for (int cc = 0; cc < 2; ++cc) {
        const int c = c0 + cc;
        const float* __restrict__ pl = img + ((b * 16 + c) << 12) + x;

#pragma unroll
        for (int i = 0; i < 5; ++i) {
            const int yy = y + i - 2;                 // wave-uniform
            float v = ((unsigned)yy < 64u) ? pl[yy << 6] : NEG_INF;
            // DPP neighbor exchange; -inf substituted at wave edges.
            float vm1 = sh_m1(v);
            float vm2 = sh_m1(vm1);
            float vp1 = sh_p1(v);
            float vp2 = sh_p1(vp1);
            const f32x2 P01 = (f32x2){vm2, vm1};      // taps j=0,1 (cols x-2,x-1)
            const f32x2 P23 = (f32x2){v, vp1};        // taps j=2,3 (cols x,x+1)
            // vp2 = tap j=4 (col x+2), scalar.

            const int kb = 24 - 5 * i;                // weight idx for tap j: kb - j
#pragma unroll
            for (int oo = 0; oo < 4; ++oo) {
                const float* __restrict__ kp = kern + ((o0 + oo) * 16 + c) * 25;
                const f32x2 W01 = (f32x2){kp[kb],     kp[kb - 1]};
                const f32x2 W23 = (f32x2){kp[kb - 2], kp[kb - 3]};
                accP[oo] = __builtin_elementwise_max(accP[oo], P01 + W01);
                accP[oo] = __builtin_elementwise_max(accP[oo], P23 + W23);
                accS[oo] = fmaxf(accS[oo], vp2 + kp[kb - 4]);
            }
        }
    }

    // Cross-wave max reduction (each wave covered 2 of 16 channels).
#pragma unroll
    for (int oo = 0; oo < 4; ++oo)
        red[w][oo][x] = fmaxf(fmaxf(accP[oo].x, accP[oo].y), accS[oo]);
    __syncthreads();

    if (threadIdx.x < 256) {
        const int oo = threadIdx.x >> 6;
        float r = red[0][oo][x];
#pragma unroll
        for (int ww = 1; ww < 8; ++ww) r = fmaxf(r, red[ww][oo][x]);
        out[((b * 16 + o0 + oo) << 12) + (y << 6) + x] = r;
    }
}

extern "C" void kernel_launch(void* const* d_in, const int* in_sizes, int n_in,
                              void* d_out, int out_size, void* d_ws, size_t ws_size,
                              hipStream_t stream) {
    const float* img  = (const float*)d_in[0];   // (4,16,64,64)
    const float* kern = (const float*)d_in[1];   // (16,16,5,5)
    float* out = (float*)d_out;                  // (4,16,64,64)
    (void)in_sizes; (void)n_in; (void)out_size; (void)d_ws; (void)ws_size;

    dim3 grid(64, 4, 4);   // y, o/4, b -> 1024 blocks * 8 waves = 32 waves/CU
    hipLaunchKernelGGL(bconv_kernel, grid, dim3(512), 0, stream, img, kern, out);
}

// Round 8
// 65.925 us; speedup vs baseline: 1.3638x; 1.0327x over previous
//
#include <hip/hip_runtime.h>
#include <math.h>

// BroadcastConv (max-plus conv): out[b,o,y,x] = max_{c,i,j} img[b,c,y+i-2,x+j-2] + kern[o,c,4-i,4-j]
// B=4, C=16, O=16, H=W=64, k=5x5, pad=2 with -inf.
//
// R8 = R5 revert (measured best: bconv 4.83us marginal) + one fix:
//  - ALL 10 row loads (2 channels x 5 rows) issued as one branchless burst
//    up front (clamped row index + 1 cndmask per row, replacing the uniform
//    `continue` branch that fragmented the burst). Channel 1's VMEM latency
//    hides under channel 0's compute.
//  - neighbor taps via __shfl (ds_bpermute, LDS pipe - parallel to VALU;
//    R7 proved DPP-on-VALU is a regression).
//  - weights on the scalar pipe (readfirstlane-uniform wave id).
//  - 512-thr blocks, 8 waves, c-split 8-way, 1024 blocks -> 32 waves/CU.

#define NEG_INF (-__builtin_inff())

__global__ __launch_bounds__(512, 8) void bconv_kernel(
        const float* __restrict__ img,
        const float* __restrict__ kern,
        float* __restrict__ out) {
    const int x  = threadIdx.x & 63;                                   // lane = W col
    const int w  = __builtin_amdgcn_readfirstlane(threadIdx.x >> 6);   // wave id 0..7
    const int y  = blockIdx.x;
    const int og = blockIdx.y;
    const int b  = blockIdx.z;
    const int o0 = og * 4;
    const int c0 = w * 2;

    __shared__ float red[8][4][64];

    const bool ok0 = (x >= 2);    // tap j=0 -> col x-2
    const bool ok1 = (x >= 1);
    const bool ok3 = (x <= 62);
    const bool ok4 = (x <= 61);   // tap j=4 -> col x+2

    // ---- one branchless burst: 10 coalesced row loads (2 c x 5 rows) ----
    const float* __restrict__ pl0 = img + ((b * 16 + c0) << 12) + x;
    const float* __restrict__ pl1 = pl0 + 4096;
    int  yoff[5];
    bool yok[5];
#pragma unroll
    for (int i = 0; i < 5; ++i) {
        int yy  = y + i - 2;
        yok[i]  = (unsigned)yy < 64u;
        yoff[i] = (yok[i] ? yy : 0) << 6;     // clamped row offset
    }
    float va[5], vb[5];
#pragma unroll
    for (int i = 0; i < 5; ++i) va[i] = pl0[yoff[i]];
#pragma unroll
    for (int i = 0; i < 5; ++i) vb[i] = pl1[yoff[i]];
#pragma unroll
    for (int i = 0; i < 5; ++i) {
        va[i] = yok[i] ? va[i] : NEG_INF;     // -inf rows; shuffles propagate it
        vb[i] = yok[i] ? vb[i] : NEG_INF;
    }

    float acc0 = NEG_INF, acc1 = NEG_INF, acc2 = NEG_INF, acc3 = NEG_INF;

#pragma unroll
    for (int cc = 0; cc < 2; ++cc) {
        const int c = c0 + cc;
        const float* __restrict__ kp0 = kern + ((o0 + 0) * 16 + c) * 25;
        const float* __restrict__ kp1 = kern + ((o0 + 1) * 16 + c) * 25;
        const float* __restrict__ kp2 = kern + ((o0 + 2) * 16 + c) * 25;
        const float* __restrict__ kp3 = kern + ((o0 + 3) * 16 + c) * 25;

#pragma unroll
        for (int i = 0; i < 5; ++i) {
            float v2 = cc ? vb[i] : va[i];
            // Neighbor taps via cross-lane exchange (LDS pipe). Wrapped lanes
            // (&63) are exactly the masked-out ones.
            float v0 = __shfl(v2, x - 2);
            float v1 = __shfl(v2, x - 1);
            float v3 = __shfl(v2, x + 1);
            float v4 = __shfl(v2, x + 2);
            v0 = ok0 ? v0 : NEG_INF;
            v1 = ok1 ? v1 : NEG_INF;
            v3 = ok3 ? v3 : NEG_INF;
            v4 = ok4 ? v4 : NEG_INF;

            const int kb = 24 - 5 * i;        // weight idx for tap j is kb - j
#define ACC_O(kp, A)                                                     \
            {                                                            \
                float t0 = v0 + kp[kb - 0];                              \
                float t1 = v1 + kp[kb - 1];                              \
                float t2 = v2 + kp[kb - 2];                              \
                float t3 = v3 + kp[kb - 3];                              \
                float t4 = v4 + kp[kb - 4];                              \
                float m01  = fmaxf(t0, t1);                              \
                float m234 = fmaxf(fmaxf(t2, t3), t4);                   \
                A = fmaxf(A, fmaxf(m01, m234));                          \
            }
            ACC_O(kp0, acc0)
            ACC_O(kp1, acc1)
            ACC_O(kp2, acc2)
            ACC_O(kp3, acc3)
#undef ACC_O
        }
    }

    // Cross-wave max reduction (each wave covered 2 of 16 channels).
    red[w][0][x] = acc0;
    red[w][1][x] = acc1;
    red[w][2][x] = acc2;
    red[w][3][x] = acc3;
    __syncthreads();

    if (threadIdx.x < 256) {
        const int oo = threadIdx.x >> 6;
        float r = red[0][oo][x];
#pragma unroll
        for (int ww = 1; ww < 8; ++ww) r = fmaxf(r, red[ww][oo][x]);
        out[((b * 16 + o0 + oo) << 12) + (y << 6) + x] = r;
    }
}

extern "C" void kernel_launch(void* const* d_in, const int* in_sizes, int n_in,
                              void* d_out, int out_size, void* d_ws, size_t ws_size,
                              hipStream_t stream) {
    const float* img  = (const float*)d_in[0];   // (4,16,64,64)
    const float* kern = (const float*)d_in[1];   // (16,16,5,5)
    float* out = (float*)d_out;                  // (4,16,64,64)
    (void)in_sizes; (void)n_in; (void)out_size; (void)d_ws; (void)ws_size;

    dim3 grid(64, 4, 4);   // y, o/4, b -> 1024 blocks * 8 waves = 32 waves/CU
    hipLaunchKernelGGL(bconv_kernel, grid, dim3(512), 0, stream, img, kern, out);
}